// Round 3
// baseline (36.097 us; speedup 1.0000x reference)
//
#include <hip/hip_runtime.h>

// Chamfer loss: B=8, N1=N2=4096, D=3, fp32 in, scalar fp32 out.
// R3: packed fp32. v_pk_fma_f32 computes 2 j-points per inst (the only path
// to the 157 TF fp32 peak); v_min3_f32 folds both into the running min.
// 2 VALU insts per point-row (was 3.5). TROWS=8 amortizes LDS broadcast.

namespace {
constexpr int Bc = 8;
constexpr int Nc = 4096;
constexpr int TPB = 256;
constexpr int TROWS = 8;                      // row points per thread
constexpr int ROWS_PER_BLOCK = TPB * TROWS;   // 2048
constexpr int JCHUNK = 128;                   // other-points staged per block
constexpr int NJCH = Nc / JCHUNK;             // 32
constexpr int NRB  = Nc / ROWS_PER_BLOCK;     // 2
constexpr unsigned INF_BITS = 0x7f800000u;
}

typedef float f32x2 __attribute__((ext_vector_type(2)));

__device__ __forceinline__ f32x2 pk_fma(f32x2 a, f32x2 b, f32x2 c) {
  f32x2 d;
  asm("v_pk_fma_f32 %0, %1, %2, %3" : "=v"(d) : "v"(a), "v"(b), "v"(c));
  return d;
}
__device__ __forceinline__ float min3f(float a, float b, float c) {
  float d;
  asm("v_min3_f32 %0, %1, %2, %3" : "=v"(d) : "v"(a), "v"(b), "v"(c));
  return d;
}

// Persistent scratch (re-initialized every call -> deterministic).
__device__ unsigned int g_mins[2 * Bc * Nc];

__global__ __launch_bounds__(TPB) void init_kernel(float* out) {
  int i = blockIdx.x * TPB + threadIdx.x;
  if (i < 2 * Bc * Nc) g_mins[i] = INF_BITS;
  if (i == 0) out[0] = 0.0f;
}

__global__ __launch_bounds__(TPB, 4) void cham_kernel(const float* __restrict__ pred,
                                                      const float* __restrict__ gt) {
  const int bx     = blockIdx.x;        // [0, NRB*NJCH)
  const int rowblk = bx / NJCH;
  const int jblk   = bx % NJCH;
  const int b      = blockIdx.y;
  const int dir    = blockIdx.z;        // 0: rows=pred vs gt; 1: rows=gt vs pred

  const float* rows    = (dir == 0) ? pred : gt;
  const float* others  = (dir == 0) ? gt : pred;
  const float* rowbase = rows   + ((size_t)b * Nc + (size_t)rowblk * ROWS_PER_BLOCK) * 3;
  const float* othbase = others + ((size_t)b * Nc + (size_t)jblk * JCHUNK) * 3;
  unsigned int* minbase = g_mins + ((size_t)dir * Bc + b) * Nc + (size_t)rowblk * ROWS_PER_BLOCK;

  // Paired SoA: sXY[q]=(x0,x1,y0,y1), sZH[q]=(z0,z1,h0,h1) for points 2q,2q+1.
  __shared__ __align__(16) float4 sXY[JCHUNK / 2];
  __shared__ __align__(16) float4 sZH[JCHUNK / 2];

  const int t = threadIdx.x;
  if (t < JCHUNK / 2) {
    const float2* p = (const float2*)(othbase + 6 * t);  // 24B per pair, 8B aligned
    float2 f0 = p[0], f1 = p[1], f2 = p[2];
    float x0 = f0.x, y0 = f0.y, z0 = f1.x;
    float x1 = f1.y, y1 = f2.x, z1 = f2.y;
    float h0 = 0.5f * (x0 * x0 + y0 * y0 + z0 * z0);
    float h1 = 0.5f * (x1 * x1 + y1 * y1 + z1 * z1);
    sXY[t] = make_float4(x0, x1, y0, y1);
    sZH[t] = make_float4(z0, z1, h0, h1);
  }

  // Row points: negated coords replicated into both packed halves.
  f32x2 nx[TROWS], ny[TROWS], nz[TROWS];
  float p2[TROWS];
  #pragma unroll
  for (int r = 0; r < TROWS; ++r) {
    const float* p = rowbase + (size_t)(t + r * TPB) * 3;
    float x = p[0], y = p[1], z = p[2];
    nx[r] = (f32x2){-x, -x};
    ny[r] = (f32x2){-y, -y};
    nz[r] = (f32x2){-z, -z};
    p2[r] = x * x + y * y + z * z;
  }
  __syncthreads();

  float acc[TROWS];
  #pragma unroll
  for (int r = 0; r < TROWS; ++r) acc[r] = __builtin_inff();

  #pragma unroll 8
  for (int q = 0; q < JCHUNK / 2; ++q) {
    const float4 xy = sXY[q];   // uniform-address broadcast, conflict-free
    const float4 zh = sZH[q];
    const f32x2 Xp = {xy.x, xy.y};
    const f32x2 Yp = {xy.z, xy.w};
    const f32x2 Zp = {zh.x, zh.y};
    const f32x2 Hp = {zh.z, zh.w};
    #pragma unroll
    for (int r = 0; r < TROWS; ++r) {
      // s = h_j - p.y_j for two j at once: 3 pk_fma.
      f32x2 s = pk_fma(nx[r], Xp, pk_fma(ny[r], Yp, pk_fma(nz[r], Zp, Hp)));
      acc[r] = min3f(s.x, s.y, acc[r]);
    }
  }

  #pragma unroll
  for (int r = 0; r < TROWS; ++r) {
    float d2 = fmaf(2.0f, acc[r], p2[r]);   // ||p||^2 + ||y||^2 - 2 p.y
    d2 = fmaxf(d2, 0.0f);                   // clamp (monotone, same as per-pair)
    atomicMin(minbase + t + r * TPB, __float_as_uint(d2));
  }
}

__global__ __launch_bounds__(TPB) void reduce_kernel(float* __restrict__ out) {
  const int total = 2 * Bc * Nc;
  float s = 0.0f;
  for (int i = blockIdx.x * TPB + threadIdx.x; i < total; i += gridDim.x * TPB)
    s += __uint_as_float(g_mins[i]);
  #pragma unroll
  for (int off = 32; off > 0; off >>= 1) s += __shfl_down(s, off, 64);
  __shared__ float wsum[TPB / 64];
  const int lane = threadIdx.x & 63;
  const int wid  = threadIdx.x >> 6;
  if (lane == 0) wsum[wid] = s;
  __syncthreads();
  if (threadIdx.x == 0) {
    float tot = 0.0f;
    #pragma unroll
    for (int w = 0; w < TPB / 64; ++w) tot += wsum[w];
    atomicAdd(out, tot * (1.0f / (float)(Bc * Nc)));
  }
}

extern "C" void kernel_launch(void* const* d_in, const int* in_sizes, int n_in,
                              void* d_out, int out_size, void* d_ws, size_t ws_size,
                              hipStream_t stream) {
  const float* pred = (const float*)d_in[0];
  const float* gt   = (const float*)d_in[1];
  float* out = (float*)d_out;

  init_kernel<<<(2 * Bc * Nc + TPB - 1) / TPB, TPB, 0, stream>>>(out);

  dim3 grid(NRB * NJCH, Bc, 2);   // 64 x 8 x 2 = 1024 blocks
  cham_kernel<<<grid, TPB, 0, stream>>>(pred, gt);

  reduce_kernel<<<64, TPB, 0, stream>>>(out);
}